// Round 5
// baseline (3378.328 us; speedup 1.0000x reference)
//
#include <hip/hip_runtime.h>
#include <hip/hip_bf16.h>

#define B_   32
#define S_   200
#define H_   512
#define ED_  256
#define NF_  19
#define NROW (B_*S_)      // 6400
#define G4H  (4*H_)       // 2048
#define KIN  (ED_+NF_)    // 275
#define KP_  288          // padded K for input GEMM
#define ALD  296          // A-tile LDS row stride (bf16)
#define BH   (B_*H_)      // 16384

typedef __attribute__((ext_vector_type(8))) short short8;
typedef __attribute__((ext_vector_type(4))) float f32x4;

// ---------------- workspace layout (bytes) ----------------
#define OFF_G0    0ull
#define SZ_G0     ((size_t)NROW*G4H*2)           // 26,214,400 (bf16)
#define OFF_LSTM  (OFF_G0 + SZ_G0)
#define SZ_LSTM   ((size_t)NROW*H_*4)            // 13,107,200
#define OFF_CT    (OFF_LSTM + SZ_LSTM)
#define SZ_CT     ((size_t)NROW*NF_*4)           // 486,400
#define OFF_CN    (OFF_CT + SZ_CT)
#define OFF_H0S   (OFF_CN + SZ_CT)
#define SZ_HS     ((size_t)(S_+2)*BH*2)          // 6,619,136 (rotating bf16 slots)
#define OFF_H1S   (OFF_H0S + SZ_HS)
#define OFF_FLAGS (OFF_H1S + SZ_HS)              // 32 flags x 64 u32 stride
#define OFF_ACC   (OFF_FLAGS + 32*64*4)          // [0]=num f32, [1]=den f32
#define OFF_WB    (OFF_ACC + 64)                 // Wih0 bf16 [2048][288]

__device__ __forceinline__ unsigned short f2bf(float f) {
    unsigned u = __float_as_uint(f);
    unsigned r = u + 0x7fffu + ((u >> 16) & 1u);
    return (unsigned short)(r >> 16);
}
__device__ __forceinline__ float bf2f(unsigned short u) {
    return __uint_as_float((unsigned)u << 16);
}
__device__ __forceinline__ float sigf(float x) { return 1.0f / (1.0f + __expf(-x)); }

// ---------------- prep: c_t/c_next, h slot init, flags/accum zero ----------------
// h0 slot convention: h0 state t lives at slot t (init at slot 0).
// h1 slot convention: h1 state t lives at slot t+2 (init state "-1" at slot 1!).
//   (iteration it computes L1 state it-1 and stores at slot it+1; consumer at
//    iteration it reads slot it expecting state it-2.)
__global__ __launch_bounds__(256) void prep_kernel(
    const float* __restrict__ C, const float* __restrict__ rep,
    const float* __restrict__ past, const float* __restrict__ seq,
    const float* __restrict__ init_h,
    float* __restrict__ ct, float* __restrict__ cn,
    unsigned short* __restrict__ h0seq, unsigned short* __restrict__ h1seq,
    unsigned* __restrict__ syncbuf)
{
    int idx = blockIdx.x * 256 + threadIdx.x;
    if (idx < NROW * NF_) {
        int m = idx % NF_; int row = idx / NF_;
        int b = row / S_, s = row % S_;
        float cc = C[idx];
        float v0, v1;
        if (m < 7)       { v0 = rep [(b*(S_+1)+s)*7 + m];      v1 = rep [(b*(S_+1)+s+1)*7 + m]; }
        else if (m < 13) { v0 = seq [(b*(S_+1)+s)*6 + (m-7)];  v1 = seq [(b*(S_+1)+s+1)*6 + (m-7)]; }
        else             { v0 = past[(b*(S_+1)+s)*6 + (m-13)]; v1 = past[(b*(S_+1)+s+1)*6 + (m-13)]; }
        ct[idx] = cc * v0;
        cn[idx] = cc * v1;
    }
    int j = idx - NROW * NF_;
    if (j >= 0 && j < BH) {
        h0seq[j]      = f2bf(init_h[j]);        // slot 0
        h1seq[BH + j] = f2bf(init_h[BH + j]);   // slot 1  (fix: was slot 0)
    }
    int j2 = j - BH;
    if (j2 >= 0 && j2 < 2064) syncbuf[j2] = 0u;   // flags + accum
}

// ---------------- prep_w: Wih0 f32[2048][275] -> bf16[2048][288] (zero-pad) ----------------
__global__ __launch_bounds__(256) void prepw_kernel(
    const float* __restrict__ Wih0, unsigned short* __restrict__ wb)
{
    int idx = blockIdx.x * 256 + threadIdx.x;
    if (idx >= G4H * KP_) return;
    int k = idx % KP_; int r = idx / KP_;
    wb[idx] = (k < KIN) ? f2bf(Wih0[(size_t)r * KIN + k]) : (unsigned short)0;
}

// ---------------- G0 = [emb|c_t] @ Wih0^T + bih0 + bhh0 -> bf16 ----------------
// 3200 blocks: 200 row-tiles (32 rows) x 16 col-tiles (128 gate rows)
__global__ __launch_bounds__(256) void g0_kernel(
    const int* __restrict__ x_data, const float* __restrict__ embed,
    const unsigned short* __restrict__ wb,
    const float* __restrict__ bih0, const float* __restrict__ bhh0,
    const float* __restrict__ ct, unsigned short* __restrict__ G0b)
{
    __shared__ unsigned short A[32 * ALD];
    int tid = threadIdx.x;
    int bx = blockIdx.x;
    int mb = bx >> 4;          // 0..199
    int nb = bx & 15;          // 0..15
    int rbase = mb * 32;
    {   // stage A: 32 gathered rows of [emb(256)|c_t(19)|pad]
        int r = tid >> 3, c8 = tid & 7;
        int grow = rbase + r;
        const float* erow = embed + (size_t)x_data[grow] * ED_;
        #pragma unroll
        for (int jj = 0; jj < 8; jj++) {
            float4 v = *(const float4*)(erow + c8 * 32 + jj * 4);
            unsigned short* d = &A[r * ALD + c8 * 32 + jj * 4];
            d[0] = f2bf(v.x); d[1] = f2bf(v.y); d[2] = f2bf(v.z); d[3] = f2bf(v.w);
        }
        if (c8 == 0) {
            const float* crow = ct + (size_t)grow * NF_;
            for (int m = 0; m < NF_; m++) A[r * ALD + ED_ + m] = f2bf(crow[m]);
            for (int m = NF_; m < 32; m++) A[r * ALD + ED_ + m] = 0;
        }
    }
    __syncthreads();
    int lane = tid & 63, w = tid >> 6;
    int nc0 = nb * 128 + w * 16 + (lane & 15);
    int nc1 = nc0 + 64;
    int kb = (lane >> 4) * 8;
    f32x4 acc00 = {0.f,0.f,0.f,0.f}, acc01 = {0.f,0.f,0.f,0.f};
    f32x4 acc10 = {0.f,0.f,0.f,0.f}, acc11 = {0.f,0.f,0.f,0.f};
    #pragma unroll
    for (int ks = 0; ks < 9; ks++) {
        int k0 = ks * 32 + kb;
        short8 b0 = *(const short8*)(wb + (size_t)nc0 * KP_ + k0);
        short8 b1 = *(const short8*)(wb + (size_t)nc1 * KP_ + k0);
        short8 a0 = *(const short8*)&A[(lane & 15) * ALD + k0];
        short8 a1 = *(const short8*)&A[(16 + (lane & 15)) * ALD + k0];
        acc00 = __builtin_amdgcn_mfma_f32_16x16x32_bf16(a0, b0, acc00, 0, 0, 0);
        acc01 = __builtin_amdgcn_mfma_f32_16x16x32_bf16(a0, b1, acc01, 0, 0, 0);
        acc10 = __builtin_amdgcn_mfma_f32_16x16x32_bf16(a1, b0, acc10, 0, 0, 0);
        acc11 = __builtin_amdgcn_mfma_f32_16x16x32_bf16(a1, b1, acc11, 0, 0, 0);
    }
    float bias0 = bih0[nc0] + bhh0[nc0];
    float bias1 = bih0[nc1] + bhh0[nc1];
    #pragma unroll
    for (int r = 0; r < 4; r++) {
        int row0 = (lane >> 4) * 4 + r;
        G0b[(size_t)(rbase + row0) * G4H + nc0]      = f2bf(acc00[r] + bias0);
        G0b[(size_t)(rbase + row0) * G4H + nc1]      = f2bf(acc01[r] + bias1);
        G0b[(size_t)(rbase + 16 + row0) * G4H + nc0] = f2bf(acc10[r] + bias0);
        G0b[(size_t)(rbase + 16 + row0) * G4H + nc1] = f2bf(acc11[r] + bias1);
    }
}

// ---------------- persistent 2-layer LSTM scan ----------------
// 32 blocks x 512 threads. Block p owns units [16p, 16p+16) of each layer.
// Weights stationary in registers. h exchanged via ROTATING per-iteration
// bf16 slots: producers write through with agent-scope (sc0 sc1) stores;
// consumers use plain CACHED loads (virgin addresses each iteration).
// Grid sync via per-block flags (own line each) + lane-parallel ballot poll.
__global__ __launch_bounds__(512, 1) void scan_kernel(
    const unsigned short* __restrict__ G0b,
    const float* __restrict__ Whh0,
    const float* __restrict__ Wih1, const float* __restrict__ Whh1,
    const float* __restrict__ bih1, const float* __restrict__ bhh1,
    const float* __restrict__ init_c,
    unsigned short* __restrict__ h0seq, unsigned short* __restrict__ h1seq,
    float* __restrict__ lstm_out,
    unsigned* __restrict__ flags)
{
    __shared__ float g0l[32 * 66];             // 8448 B
    __shared__ float g1l[32 * 66];             // 8448 B
    __shared__ float c0s[16 * 33];
    __shared__ float c1s[16 * 33];
    __shared__ float bias1s[64];

    const int tid = threadIdx.x;
    const int p = blockIdx.x;                  // 0..31
    const int lane = tid & 63, w = tid >> 6;   // 8 waves
    const int mt = w & 1, nt = w >> 1;         // row-tile(2) x gate(4)
    const int l15 = lane & 15;
    const int gr = nt * H_ + p * 16 + l15;     // global gate row for B-frags
    const int kb = (lane >> 4) * 8;
    const int arow = mt * 16 + l15;            // batch row for A-frags
    const int lr = nt * 16 + l15;              // local gate col 0..63

    // stationary weight B-fragments (held in VGPR/AGPR unified file)
    short8 B0[16], B1[32];
    #pragma unroll
    for (int ks = 0; ks < 16; ks++) {
        const float* s0 = Whh0 + (size_t)gr * H_ + ks * 32 + kb;
        const float* s1 = Wih1 + (size_t)gr * H_ + ks * 32 + kb;
        const float* s2 = Whh1 + (size_t)gr * H_ + ks * 32 + kb;
        float4 a = *(const float4*)(s0), b = *(const float4*)(s0 + 4);
        short8 t0; t0[0]=f2bf(a.x);t0[1]=f2bf(a.y);t0[2]=f2bf(a.z);t0[3]=f2bf(a.w);
                   t0[4]=f2bf(b.x);t0[5]=f2bf(b.y);t0[6]=f2bf(b.z);t0[7]=f2bf(b.w);
        B0[ks] = t0;
        a = *(const float4*)(s1); b = *(const float4*)(s1 + 4);
        short8 t1; t1[0]=f2bf(a.x);t1[1]=f2bf(a.y);t1[2]=f2bf(a.z);t1[3]=f2bf(a.w);
                   t1[4]=f2bf(b.x);t1[5]=f2bf(b.y);t1[6]=f2bf(b.z);t1[7]=f2bf(b.w);
        B1[ks] = t1;
        a = *(const float4*)(s2); b = *(const float4*)(s2 + 4);
        short8 t2; t2[0]=f2bf(a.x);t2[1]=f2bf(a.y);t2[2]=f2bf(a.z);t2[3]=f2bf(a.w);
                   t2[4]=f2bf(b.x);t2[5]=f2bf(b.y);t2[6]=f2bf(b.z);t2[7]=f2bf(b.w);
        B1[16 + ks] = t2;
    }
    if (tid < 64) {
        int g = tid >> 4, u = tid & 15;
        bias1s[tid] = bih1[g * H_ + p * 16 + u] + bhh1[g * H_ + p * 16 + u];
    }
    const int uu = tid & 15, b8 = tid >> 4;    // unit, batch for epilogue
    c0s[uu * 33 + b8] = init_c[(size_t)b8 * H_ + p * 16 + uu];
    c1s[uu * 33 + b8] = init_c[(size_t)BH + (size_t)b8 * H_ + p * 16 + uu];
    __syncthreads();

    for (int it = 0; it <= S_; it++) {
        // A-fragments: h0 state[it] (slot it), h1 state[it-2] (slot it)
        const unsigned short* p0 = h0seq + (size_t)it * BH + (size_t)arow * H_ + kb;
        const unsigned short* p1 = h1seq + (size_t)it * BH + (size_t)arow * H_ + kb;
        short8 F0[16], F1[16];
        #pragma unroll
        for (int ks = 0; ks < 16; ks++) {
            F0[ks] = *(const short8*)(p0 + ks * 32);
            F1[ks] = *(const short8*)(p1 + ks * 32);
        }
        // G0 pre-activations for epilogue (bf16, L3-resident stream)
        float gp0 = 0.f, gp1 = 0.f, gp2 = 0.f, gp3 = 0.f;
        if (it < S_) {
            const unsigned short* gsrc = G0b + (size_t)(b8 * S_ + it) * G4H + p * 16 + uu;
            gp0 = bf2f(gsrc[0]);      gp1 = bf2f(gsrc[H_]);
            gp2 = bf2f(gsrc[2 * H_]); gp3 = bf2f(gsrc[3 * H_]);
        }

        f32x4 acc0 = {0.f,0.f,0.f,0.f};
        f32x4 a1a  = {0.f,0.f,0.f,0.f};
        f32x4 a1b  = {0.f,0.f,0.f,0.f};
        #pragma unroll
        for (int ks = 0; ks < 16; ks++) {
            acc0 = __builtin_amdgcn_mfma_f32_16x16x32_bf16(F0[ks], B0[ks],      acc0, 0, 0, 0);
            a1a  = __builtin_amdgcn_mfma_f32_16x16x32_bf16(F0[ks], B1[ks],      a1a,  0, 0, 0);
            a1b  = __builtin_amdgcn_mfma_f32_16x16x32_bf16(F1[ks], B1[16 + ks], a1b,  0, 0, 0);
        }
        #pragma unroll
        for (int r = 0; r < 4; r++) {
            int row = mt * 16 + (lane >> 4) * 4 + r;
            g0l[row * 66 + lr] = acc0[r];
            g1l[row * 66 + lr] = a1a[r] + a1b[r];
        }
        __syncthreads();

        if (it < S_) {
            float iv = g0l[b8 * 66 + uu]      + gp0;
            float fv = g0l[b8 * 66 + 16 + uu] + gp1;
            float gv = g0l[b8 * 66 + 32 + uu] + gp2;
            float ov = g0l[b8 * 66 + 48 + uu] + gp3;
            float c = c0s[uu * 33 + b8];
            c = sigf(fv) * c + sigf(iv) * tanhf(gv);
            c0s[uu * 33 + b8] = c;
            float h = sigf(ov) * tanhf(c);
            float hn = __shfl_down(h, 1, 64);
            if (!(uu & 1)) {
                unsigned pk = (unsigned)f2bf(h) | ((unsigned)f2bf(hn) << 16);
                __hip_atomic_store(
                    (unsigned*)(h0seq + (size_t)(it + 1) * BH + (size_t)b8 * H_ + p * 16 + uu),
                    pk, __ATOMIC_RELAXED, __HIP_MEMORY_SCOPE_AGENT);
            }
        }
        if (it >= 1) {
            float iv = g1l[b8 * 66 + uu]      + bias1s[uu];
            float fv = g1l[b8 * 66 + 16 + uu] + bias1s[16 + uu];
            float gv = g1l[b8 * 66 + 32 + uu] + bias1s[32 + uu];
            float ov = g1l[b8 * 66 + 48 + uu] + bias1s[48 + uu];
            float c = c1s[uu * 33 + b8];
            c = sigf(fv) * c + sigf(iv) * tanhf(gv);
            c1s[uu * 33 + b8] = c;
            float h = sigf(ov) * tanhf(c);
            float hn = __shfl_down(h, 1, 64);
            if (!(uu & 1)) {
                unsigned pk = (unsigned)f2bf(h) | ((unsigned)f2bf(hn) << 16);
                __hip_atomic_store(
                    (unsigned*)(h1seq + (size_t)(it + 1) * BH + (size_t)b8 * H_ + p * 16 + uu),
                    pk, __ATOMIC_RELAXED, __HIP_MEMORY_SCOPE_AGENT);
            }
            lstm_out[(size_t)(b8 * S_ + (it - 1)) * H_ + p * 16 + uu] = h;
        }

        if (it < S_) {
            // drain own h stores to coherence point, publish flag, poll all
            asm volatile("s_waitcnt vmcnt(0)" ::: "memory");
            __syncthreads();
            if (tid == 0)
                __hip_atomic_store(&flags[p * 64], (unsigned)(it + 1),
                                   __ATOMIC_RELAXED, __HIP_MEMORY_SCOPE_AGENT);
            if (tid < 64) {
                const unsigned* fp = &flags[(tid & 31) * 64];
                const unsigned tgt = (unsigned)(it + 1);
                while (__ballot(__hip_atomic_load(fp, __ATOMIC_RELAXED,
                                                  __HIP_MEMORY_SCOPE_AGENT) < tgt) != 0ull) {}
            }
            __syncthreads();
            asm volatile("" ::: "memory");     // no load hoisting above the barrier
        }
    }
}

// ---------------- gathered prediction + BCE ----------------
__global__ __launch_bounds__(256) void pred_kernel(
    const float* __restrict__ lstm_out, const float* __restrict__ cn,
    const float* __restrict__ Wp, const float* __restrict__ bp,
    const int* __restrict__ qt, const float* __restrict__ target,
    float* __restrict__ out, float* __restrict__ accum)
{
    int wv = (blockIdx.x * 256 + threadIdx.x) >> 6;   // one wave per row
    int lane = threadIdx.x & 63;
    if (wv >= NROW) return;
    int q = qt[wv];
    const float* wrow = Wp + (size_t)q * (H_ + NF_);
    const float* hrow = lstm_out + (size_t)wv * H_;
    float part = 0.f;
    #pragma unroll
    for (int i = 0; i < H_ / 64; i++) part += hrow[lane + i * 64] * wrow[lane + i * 64];
    if (lane < NF_) part += cn[(size_t)wv * NF_ + lane] * wrow[H_ + lane];
    #pragma unroll
    for (int off = 32; off; off >>= 1) part += __shfl_down(part, off, 64);
    if (lane == 0) {
        float x = part + bp[q];
        float t = target[wv];
        float mask = (q > 0) ? 1.f : 0.f;
        out[1 + wv] = mask / (1.f + __expf(-x));
        out[1 + NROW + wv] = t * mask;
        float bce = fmaxf(x, 0.f) - x * t + log1pf(__expf(-fabsf(x)));
        atomicAdd(&accum[0], bce * mask);
        atomicAdd(&accum[1], mask);
    }
}

__global__ void final_kernel(const float* __restrict__ accum, float* __restrict__ out)
{
    out[0] = accum[0] / accum[1];
}

extern "C" void kernel_launch(void* const* d_in, const int* in_sizes, int n_in,
                              void* d_out, int out_size, void* d_ws, size_t ws_size,
                              hipStream_t stream)
{
    (void)in_sizes; (void)n_in; (void)out_size; (void)ws_size;
    const int*   x_data = (const int*)  d_in[0];
    const int*   q_t    = (const int*)  d_in[1];
    const float* target = (const float*)d_in[2];
    const float* rep    = (const float*)d_in[3];
    const float* past   = (const float*)d_in[4];
    const float* seq    = (const float*)d_in[5];
    const float* embed  = (const float*)d_in[6];
    const float* Wih0   = (const float*)d_in[7];
    const float* Whh0   = (const float*)d_in[8];
    const float* bih0   = (const float*)d_in[9];
    const float* bhh0   = (const float*)d_in[10];
    const float* Wih1   = (const float*)d_in[11];
    const float* Whh1   = (const float*)d_in[12];
    const float* bih1   = (const float*)d_in[13];
    const float* bhh1   = (const float*)d_in[14];
    const float* Wp     = (const float*)d_in[15];
    const float* bp     = (const float*)d_in[16];
    const float* C      = (const float*)d_in[17];
    const float* init_h = (const float*)d_in[18];
    const float* init_c = (const float*)d_in[19];

    char* ws = (char*)d_ws;
    unsigned short* G0b   = (unsigned short*)(ws + OFF_G0);
    float*          lstm  = (float*)         (ws + OFF_LSTM);
    float*          ct    = (float*)         (ws + OFF_CT);
    float*          cn    = (float*)         (ws + OFF_CN);
    unsigned short* h0seq = (unsigned short*)(ws + OFF_H0S);
    unsigned short* h1seq = (unsigned short*)(ws + OFF_H1S);
    unsigned*       flags = (unsigned*)      (ws + OFF_FLAGS);
    float*          accum = (float*)         (ws + OFF_ACC);
    unsigned short* wb    = (unsigned short*)(ws + OFF_WB);
    float* out = (float*)d_out;

    prep_kernel<<<548, 256, 0, stream>>>(C, rep, past, seq, init_h, ct, cn,
                                         h0seq, h1seq, flags);
    prepw_kernel<<<(G4H * KP_ + 255) / 256, 256, 0, stream>>>(Wih0, wb);
    g0_kernel<<<3200, 256, 0, stream>>>(x_data, embed, wb, bih0, bhh0, ct, G0b);
    scan_kernel<<<32, 512, 0, stream>>>(G0b, Whh0, Wih1, Whh1, bih1, bhh1, init_c,
                                        h0seq, h1seq, lstm, flags);
    pred_kernel<<<NROW / 4, 256, 0, stream>>>(lstm, cn, Wp, bp, q_t, target, out, accum);
    final_kernel<<<1, 1, 0, stream>>>(accum, out);
}

// Round 6
// 2388.073 us; speedup vs baseline: 1.4147x; 1.4147x over previous
//
#include <hip/hip_runtime.h>
#include <hip/hip_bf16.h>

#define B_   32
#define S_   200
#define H_   512
#define ED_  256
#define NF_  19
#define NROW (B_*S_)      // 6400
#define G4H  (4*H_)       // 2048
#define KIN  (ED_+NF_)    // 275
#define KP_  288          // padded K for input GEMM
#define ALD  296          // A-tile LDS row stride (bf16)
#define BH   (B_*H_)      // 16384

typedef __attribute__((ext_vector_type(8))) short short8;
typedef __attribute__((ext_vector_type(4))) float f32x4;

// ---------------- workspace layout (bytes) ----------------
#define OFF_G0    0ull
#define SZ_G0     ((size_t)NROW*G4H*2)           // 26,214,400 (bf16)
#define OFF_LSTM  (OFF_G0 + SZ_G0)
#define SZ_LSTM   ((size_t)NROW*H_*4)            // 13,107,200
#define OFF_CT    (OFF_LSTM + SZ_LSTM)
#define SZ_CT     ((size_t)NROW*NF_*4)           // 486,400
#define OFF_CN    (OFF_CT + SZ_CT)
#define OFF_H0S   (OFF_CN + SZ_CT)
#define SZ_HS     ((size_t)(S_+2)*BH*2)          // 6,619,136 (rotating bf16 slots)
#define OFF_H1S   (OFF_H0S + SZ_HS)
#define OFF_FLAGS (OFF_H1S + SZ_HS)              // 32 flags x 64 u32 stride
#define OFF_ACC   (OFF_FLAGS + 32*64*4)          // [0]=num f32, [1]=den f32
#define OFF_WB    (OFF_ACC + 64)                 // Wih0 bf16 [2048][288]

__device__ __forceinline__ unsigned short f2bf(float f) {
    unsigned u = __float_as_uint(f);
    unsigned r = u + 0x7fffu + ((u >> 16) & 1u);
    return (unsigned short)(r >> 16);
}
__device__ __forceinline__ float bf2f(unsigned short u) {
    return __uint_as_float((unsigned)u << 16);
}
__device__ __forceinline__ float sigf(float x) { return 1.0f / (1.0f + __expf(-x)); }

// ---------------- prep: c_t/c_next, h slot init, flags/accum zero ----------------
// h0: state t at slot t (init at slot 0). h1: state t at slot t+2 (init at slot 1).
__global__ __launch_bounds__(256) void prep_kernel(
    const float* __restrict__ C, const float* __restrict__ rep,
    const float* __restrict__ past, const float* __restrict__ seq,
    const float* __restrict__ init_h,
    float* __restrict__ ct, float* __restrict__ cn,
    unsigned short* __restrict__ h0seq, unsigned short* __restrict__ h1seq,
    unsigned* __restrict__ syncbuf)
{
    int idx = blockIdx.x * 256 + threadIdx.x;
    if (idx < NROW * NF_) {
        int m = idx % NF_; int row = idx / NF_;
        int b = row / S_, s = row % S_;
        float cc = C[idx];
        float v0, v1;
        if (m < 7)       { v0 = rep [(b*(S_+1)+s)*7 + m];      v1 = rep [(b*(S_+1)+s+1)*7 + m]; }
        else if (m < 13) { v0 = seq [(b*(S_+1)+s)*6 + (m-7)];  v1 = seq [(b*(S_+1)+s+1)*6 + (m-7)]; }
        else             { v0 = past[(b*(S_+1)+s)*6 + (m-13)]; v1 = past[(b*(S_+1)+s+1)*6 + (m-13)]; }
        ct[idx] = cc * v0;
        cn[idx] = cc * v1;
    }
    int j = idx - NROW * NF_;
    if (j >= 0 && j < BH) {
        h0seq[j]      = f2bf(init_h[j]);        // slot 0
        h1seq[BH + j] = f2bf(init_h[BH + j]);   // slot 1
    }
    int j2 = j - BH;
    if (j2 >= 0 && j2 < 2064) syncbuf[j2] = 0u;   // flags + accum
}

// ---------------- prep_w: Wih0 f32[2048][275] -> bf16[2048][288] (zero-pad) ----------------
__global__ __launch_bounds__(256) void prepw_kernel(
    const float* __restrict__ Wih0, unsigned short* __restrict__ wb)
{
    int idx = blockIdx.x * 256 + threadIdx.x;
    if (idx >= G4H * KP_) return;
    int k = idx % KP_; int r = idx / KP_;
    wb[idx] = (k < KIN) ? f2bf(Wih0[(size_t)r * KIN + k]) : (unsigned short)0;
}

// ---------------- G0 = [emb|c_t] @ Wih0^T + bih0 + bhh0 -> bf16 ----------------
// 3200 blocks: 200 row-tiles (32 rows) x 16 col-tiles (128 gate rows)
__global__ __launch_bounds__(256) void g0_kernel(
    const int* __restrict__ x_data, const float* __restrict__ embed,
    const unsigned short* __restrict__ wb,
    const float* __restrict__ bih0, const float* __restrict__ bhh0,
    const float* __restrict__ ct, unsigned short* __restrict__ G0b)
{
    __shared__ unsigned short A[32 * ALD];
    int tid = threadIdx.x;
    int bx = blockIdx.x;
    int mb = bx >> 4;          // 0..199
    int nb = bx & 15;          // 0..15
    int rbase = mb * 32;
    {   // stage A: 32 gathered rows of [emb(256)|c_t(19)|pad]
        int r = tid >> 3, c8 = tid & 7;
        int grow = rbase + r;
        const float* erow = embed + (size_t)x_data[grow] * ED_;
        #pragma unroll
        for (int jj = 0; jj < 8; jj++) {
            float4 v = *(const float4*)(erow + c8 * 32 + jj * 4);
            unsigned short* d = &A[r * ALD + c8 * 32 + jj * 4];
            d[0] = f2bf(v.x); d[1] = f2bf(v.y); d[2] = f2bf(v.z); d[3] = f2bf(v.w);
        }
        if (c8 == 0) {
            const float* crow = ct + (size_t)grow * NF_;
            for (int m = 0; m < NF_; m++) A[r * ALD + ED_ + m] = f2bf(crow[m]);
            for (int m = NF_; m < 32; m++) A[r * ALD + ED_ + m] = 0;
        }
    }
    __syncthreads();
    int lane = tid & 63, w = tid >> 6;
    int nc0 = nb * 128 + w * 16 + (lane & 15);
    int nc1 = nc0 + 64;
    int kb = (lane >> 4) * 8;
    f32x4 acc00 = {0.f,0.f,0.f,0.f}, acc01 = {0.f,0.f,0.f,0.f};
    f32x4 acc10 = {0.f,0.f,0.f,0.f}, acc11 = {0.f,0.f,0.f,0.f};
    #pragma unroll
    for (int ks = 0; ks < 9; ks++) {
        int k0 = ks * 32 + kb;
        short8 b0 = *(const short8*)(wb + (size_t)nc0 * KP_ + k0);
        short8 b1 = *(const short8*)(wb + (size_t)nc1 * KP_ + k0);
        short8 a0 = *(const short8*)&A[(lane & 15) * ALD + k0];
        short8 a1 = *(const short8*)&A[(16 + (lane & 15)) * ALD + k0];
        acc00 = __builtin_amdgcn_mfma_f32_16x16x32_bf16(a0, b0, acc00, 0, 0, 0);
        acc01 = __builtin_amdgcn_mfma_f32_16x16x32_bf16(a0, b1, acc01, 0, 0, 0);
        acc10 = __builtin_amdgcn_mfma_f32_16x16x32_bf16(a1, b0, acc10, 0, 0, 0);
        acc11 = __builtin_amdgcn_mfma_f32_16x16x32_bf16(a1, b1, acc11, 0, 0, 0);
    }
    float bias0 = bih0[nc0] + bhh0[nc0];
    float bias1 = bih0[nc1] + bhh0[nc1];
    #pragma unroll
    for (int r = 0; r < 4; r++) {
        int row0 = (lane >> 4) * 4 + r;
        G0b[(size_t)(rbase + row0) * G4H + nc0]      = f2bf(acc00[r] + bias0);
        G0b[(size_t)(rbase + row0) * G4H + nc1]      = f2bf(acc01[r] + bias1);
        G0b[(size_t)(rbase + 16 + row0) * G4H + nc0] = f2bf(acc10[r] + bias0);
        G0b[(size_t)(rbase + 16 + row0) * G4H + nc1] = f2bf(acc11[r] + bias1);
    }
}

// ---------------- persistent 2-layer LSTM scan ----------------
// 32 blocks x 512 threads. Block p owns units [16p, 16p+16) of each layer.
// Weights stationary in registers/AGPRs. h exchanged via ROTATING bf16 slots:
// producers write through (agent-scope), consumers plain cached loads (virgin
// addresses). Flag-per-block barrier with s_sleep-backed poll (32 lanes).
__global__ __launch_bounds__(512, 1) void scan_kernel(
    const unsigned short* __restrict__ G0b,
    const float* __restrict__ Whh0,
    const float* __restrict__ Wih1, const float* __restrict__ Whh1,
    const float* __restrict__ bih1, const float* __restrict__ bhh1,
    const float* __restrict__ init_c,
    unsigned short* __restrict__ h0seq, unsigned short* __restrict__ h1seq,
    float* __restrict__ lstm_out,
    unsigned* __restrict__ flags)
{
    __shared__ float g0l[32 * 66];             // 8448 B
    __shared__ float g1l[32 * 66];             // 8448 B
    __shared__ float c0s[16 * 33];
    __shared__ float c1s[16 * 33];
    __shared__ float bias1s[64];

    const int tid = threadIdx.x;
    const int p = blockIdx.x;                  // 0..31
    const int lane = tid & 63, w = tid >> 6;   // 8 waves
    const int mt = w & 1, nt = w >> 1;         // row-tile(2) x gate(4)
    const int l15 = lane & 15;
    const int gr = nt * H_ + p * 16 + l15;     // global gate row for B-frags
    const int kb = (lane >> 4) * 8;
    const int arow = mt * 16 + l15;            // batch row for A-frags
    const int lr = nt * 16 + l15;              // local gate col 0..63

    // stationary weight B-fragments (unified VGPR/AGPR file)
    short8 B0[16], B1[32];
    #pragma unroll
    for (int ks = 0; ks < 16; ks++) {
        const float* s0 = Whh0 + (size_t)gr * H_ + ks * 32 + kb;
        const float* s1 = Wih1 + (size_t)gr * H_ + ks * 32 + kb;
        const float* s2 = Whh1 + (size_t)gr * H_ + ks * 32 + kb;
        float4 a = *(const float4*)(s0), b = *(const float4*)(s0 + 4);
        short8 t0; t0[0]=f2bf(a.x);t0[1]=f2bf(a.y);t0[2]=f2bf(a.z);t0[3]=f2bf(a.w);
                   t0[4]=f2bf(b.x);t0[5]=f2bf(b.y);t0[6]=f2bf(b.z);t0[7]=f2bf(b.w);
        B0[ks] = t0;
        a = *(const float4*)(s1); b = *(const float4*)(s1 + 4);
        short8 t1; t1[0]=f2bf(a.x);t1[1]=f2bf(a.y);t1[2]=f2bf(a.z);t1[3]=f2bf(a.w);
                   t1[4]=f2bf(b.x);t1[5]=f2bf(b.y);t1[6]=f2bf(b.z);t1[7]=f2bf(b.w);
        B1[ks] = t1;
        a = *(const float4*)(s2); b = *(const float4*)(s2 + 4);
        short8 t2; t2[0]=f2bf(a.x);t2[1]=f2bf(a.y);t2[2]=f2bf(a.z);t2[3]=f2bf(a.w);
                   t2[4]=f2bf(b.x);t2[5]=f2bf(b.y);t2[6]=f2bf(b.z);t2[7]=f2bf(b.w);
        B1[16 + ks] = t2;
    }
    if (tid < 64) {
        int g = tid >> 4, u = tid & 15;
        bias1s[tid] = bih1[g * H_ + p * 16 + u] + bhh1[g * H_ + p * 16 + u];
    }
    const int uu = tid & 15, b8 = tid >> 4;    // unit, batch for epilogue
    c0s[uu * 33 + b8] = init_c[(size_t)b8 * H_ + p * 16 + uu];
    c1s[uu * 33 + b8] = init_c[(size_t)BH + (size_t)b8 * H_ + p * 16 + uu];
    __syncthreads();

    // G0 pre-activations for it=0 (pipelined across the barrier thereafter)
    const unsigned short* gbase = G0b + (size_t)b8 * S_ * G4H + p * 16 + uu;
    float gp0 = bf2f(gbase[0]),      gp1 = bf2f(gbase[H_]);
    float gp2 = bf2f(gbase[2 * H_]), gp3 = bf2f(gbase[3 * H_]);

    for (int it = 0; it <= S_; it++) {
        // A-fragments: h0 state[it] (slot it), h1 state[it-2] (slot it)
        const unsigned short* p0 = h0seq + (size_t)it * BH + (size_t)arow * H_ + kb;
        const unsigned short* p1 = h1seq + (size_t)it * BH + (size_t)arow * H_ + kb;
        short8 F0[16], F1[16];
        #pragma unroll
        for (int ks = 0; ks < 16; ks++) {
            F0[ks] = *(const short8*)(p0 + ks * 32);
            F1[ks] = *(const short8*)(p1 + ks * 32);
        }

        f32x4 acc0 = {0.f,0.f,0.f,0.f};
        f32x4 a1a  = {0.f,0.f,0.f,0.f};
        f32x4 a1b  = {0.f,0.f,0.f,0.f};
        #pragma unroll
        for (int ks = 0; ks < 16; ks++) {
            acc0 = __builtin_amdgcn_mfma_f32_16x16x32_bf16(F0[ks], B0[ks],      acc0, 0, 0, 0);
            a1a  = __builtin_amdgcn_mfma_f32_16x16x32_bf16(F0[ks], B1[ks],      a1a,  0, 0, 0);
            a1b  = __builtin_amdgcn_mfma_f32_16x16x32_bf16(F1[ks], B1[16 + ks], a1b,  0, 0, 0);
        }
        #pragma unroll
        for (int r = 0; r < 4; r++) {
            int row = mt * 16 + (lane >> 4) * 4 + r;
            g0l[row * 66 + lr] = acc0[r];
            g1l[row * 66 + lr] = a1a[r] + a1b[r];
        }
        __syncthreads();

        if (it < S_) {
            float iv = g0l[b8 * 66 + uu]      + gp0;
            float fv = g0l[b8 * 66 + 16 + uu] + gp1;
            float gv = g0l[b8 * 66 + 32 + uu] + gp2;
            float ov = g0l[b8 * 66 + 48 + uu] + gp3;
            float c = c0s[uu * 33 + b8];
            c = sigf(fv) * c + sigf(iv) * tanhf(gv);
            c0s[uu * 33 + b8] = c;
            float h = sigf(ov) * tanhf(c);
            float hn = __shfl_down(h, 1, 64);
            if (!(uu & 1)) {
                unsigned pk = (unsigned)f2bf(h) | ((unsigned)f2bf(hn) << 16);
                __hip_atomic_store(
                    (unsigned*)(h0seq + (size_t)(it + 1) * BH + (size_t)b8 * H_ + p * 16 + uu),
                    pk, __ATOMIC_RELAXED, __HIP_MEMORY_SCOPE_AGENT);
            }
        }
        if (it >= 1) {
            float iv = g1l[b8 * 66 + uu]      + bias1s[uu];
            float fv = g1l[b8 * 66 + 16 + uu] + bias1s[16 + uu];
            float gv = g1l[b8 * 66 + 32 + uu] + bias1s[32 + uu];
            float ov = g1l[b8 * 66 + 48 + uu] + bias1s[48 + uu];
            float c = c1s[uu * 33 + b8];
            c = sigf(fv) * c + sigf(iv) * tanhf(gv);
            c1s[uu * 33 + b8] = c;
            float h = sigf(ov) * tanhf(c);
            float hn = __shfl_down(h, 1, 64);
            if (!(uu & 1)) {
                unsigned pk = (unsigned)f2bf(h) | ((unsigned)f2bf(hn) << 16);
                __hip_atomic_store(
                    (unsigned*)(h1seq + (size_t)(it + 1) * BH + (size_t)b8 * H_ + p * 16 + uu),
                    pk, __ATOMIC_RELAXED, __HIP_MEMORY_SCOPE_AGENT);
            }
            lstm_out[(size_t)(b8 * S_ + (it - 1)) * H_ + p * 16 + uu] = h;
        }

        if (it < S_) {
            // prefetch next iteration's G0 pre-activations (static data) so the
            // post-barrier critical path is only the h fetch
            if (it + 1 < S_) {
                const unsigned short* gsrc = gbase + (size_t)(it + 1) * G4H;
                gp0 = bf2f(gsrc[0]);      gp1 = bf2f(gsrc[H_]);
                gp2 = bf2f(gsrc[2 * H_]); gp3 = bf2f(gsrc[3 * H_]);
            }
            // drain own h stores to the coherence point, publish flag
            asm volatile("s_waitcnt vmcnt(0)" ::: "memory");
            __syncthreads();
            if (tid == 0)
                __hip_atomic_store(&flags[p * 64], (unsigned)(it + 1),
                                   __ATOMIC_RELAXED, __HIP_MEMORY_SCOPE_AGENT);
            // backed-off poll: 32 lanes of wave 0, one flag each; the divergent
            // loop exits when every lane has seen its flag; s_sleep(2) (~128 cyc)
            // between rounds keeps the MALL free for the arriving flag stores.
            if (tid < 32) {
                const unsigned* fp = &flags[tid * 64];
                const unsigned tgt = (unsigned)(it + 1);
                while (__hip_atomic_load(fp, __ATOMIC_RELAXED,
                                         __HIP_MEMORY_SCOPE_AGENT) < tgt) {
                    __builtin_amdgcn_s_sleep(2);
                }
            }
            __syncthreads();
            asm volatile("" ::: "memory");     // no load hoisting above the barrier
        }
    }
}

// ---------------- gathered prediction + BCE ----------------
__global__ __launch_bounds__(256) void pred_kernel(
    const float* __restrict__ lstm_out, const float* __restrict__ cn,
    const float* __restrict__ Wp, const float* __restrict__ bp,
    const int* __restrict__ qt, const float* __restrict__ target,
    float* __restrict__ out, float* __restrict__ accum)
{
    int wv = (blockIdx.x * 256 + threadIdx.x) >> 6;   // one wave per row
    int lane = threadIdx.x & 63;
    if (wv >= NROW) return;
    int q = qt[wv];
    const float* wrow = Wp + (size_t)q * (H_ + NF_);
    const float* hrow = lstm_out + (size_t)wv * H_;
    float part = 0.f;
    #pragma unroll
    for (int i = 0; i < H_ / 64; i++) part += hrow[lane + i * 64] * wrow[lane + i * 64];
    if (lane < NF_) part += cn[(size_t)wv * NF_ + lane] * wrow[H_ + lane];
    #pragma unroll
    for (int off = 32; off; off >>= 1) part += __shfl_down(part, off, 64);
    if (lane == 0) {
        float x = part + bp[q];
        float t = target[wv];
        float mask = (q > 0) ? 1.f : 0.f;
        out[1 + wv] = mask / (1.f + __expf(-x));
        out[1 + NROW + wv] = t * mask;
        float bce = fmaxf(x, 0.f) - x * t + log1pf(__expf(-fabsf(x)));
        atomicAdd(&accum[0], bce * mask);
        atomicAdd(&accum[1], mask);
    }
}

__global__ void final_kernel(const float* __restrict__ accum, float* __restrict__ out)
{
    out[0] = accum[0] / accum[1];
}

extern "C" void kernel_launch(void* const* d_in, const int* in_sizes, int n_in,
                              void* d_out, int out_size, void* d_ws, size_t ws_size,
                              hipStream_t stream)
{
    (void)in_sizes; (void)n_in; (void)out_size; (void)ws_size;
    const int*   x_data = (const int*)  d_in[0];
    const int*   q_t    = (const int*)  d_in[1];
    const float* target = (const float*)d_in[2];
    const float* rep    = (const float*)d_in[3];
    const float* past   = (const float*)d_in[4];
    const float* seq    = (const float*)d_in[5];
    const float* embed  = (const float*)d_in[6];
    const float* Wih0   = (const float*)d_in[7];
    const float* Whh0   = (const float*)d_in[8];
    const float* bih0   = (const float*)d_in[9];
    const float* bhh0   = (const float*)d_in[10];
    const float* Wih1   = (const float*)d_in[11];
    const float* Whh1   = (const float*)d_in[12];
    const float* bih1   = (const float*)d_in[13];
    const float* bhh1   = (const float*)d_in[14];
    const float* Wp     = (const float*)d_in[15];
    const float* bp     = (const float*)d_in[16];
    const float* C      = (const float*)d_in[17];
    const float* init_h = (const float*)d_in[18];
    const float* init_c = (const float*)d_in[19];

    char* ws = (char*)d_ws;
    unsigned short* G0b   = (unsigned short*)(ws + OFF_G0);
    float*          lstm  = (float*)         (ws + OFF_LSTM);
    float*          ct    = (float*)         (ws + OFF_CT);
    float*          cn    = (float*)         (ws + OFF_CN);
    unsigned short* h0seq = (unsigned short*)(ws + OFF_H0S);
    unsigned short* h1seq = (unsigned short*)(ws + OFF_H1S);
    unsigned*       flags = (unsigned*)      (ws + OFF_FLAGS);
    float*          accum = (float*)         (ws + OFF_ACC);
    unsigned short* wb    = (unsigned short*)(ws + OFF_WB);
    float* out = (float*)d_out;

    prep_kernel<<<548, 256, 0, stream>>>(C, rep, past, seq, init_h, ct, cn,
                                         h0seq, h1seq, flags);
    prepw_kernel<<<(G4H * KP_ + 255) / 256, 256, 0, stream>>>(Wih0, wb);
    g0_kernel<<<3200, 256, 0, stream>>>(x_data, embed, wb, bih0, bhh0, ct, G0b);
    scan_kernel<<<32, 512, 0, stream>>>(G0b, Whh0, Wih1, Whh1, bih1, bhh1, init_c,
                                        h0seq, h1seq, lstm, flags);
    pred_kernel<<<NROW / 4, 256, 0, stream>>>(lstm, cn, Wp, bp, q_t, target, out, accum);
    final_kernel<<<1, 1, 0, stream>>>(accum, out);
}